// Round 2
// baseline (8519.497 us; speedup 1.0000x reference)
//
#include <hip/hip_runtime.h>
#include <hip/hip_bf16.h>

// StaticCrossAttention on MI355X (gfx950). Inputs/output fp32 (per reference);
// internal compute bf16 MFMA with fp32 accumulation; intermediates bf16 in ws.
//   q = rmsnorm(hs @ Wq + bq, gq); kv = ctx @ Wkv + bkv; k = rmsnorm(kv[:DIM], gk)
//   out = softmax(q kT * sc) v ;  y = out @ Wo + bo
// Round 2: fp32-input fix. Same structure as round 1 otherwise.

typedef __hip_bfloat16 bf16;
typedef unsigned short u16;
typedef __bf16 bf16x8 __attribute__((ext_vector_type(8)));
typedef float f32x4 __attribute__((ext_vector_type(4)));
typedef u16 u16x8 __attribute__((ext_vector_type(8)));

#define DIMC 5120
#define H_ 40
#define HD_ 128
#define B_ 2
#define S_ 4096
#define L_ 512
#define EPSF 1e-6f
#define SCALEF 0.08838834764831845f  // 128^-0.5

__device__ __forceinline__ float b2f(u16 x) {
    return __uint_as_float(((unsigned)x) << 16);
}
__device__ __forceinline__ u16 f2b(float f) {
    bf16 t = __float2bfloat16(f);
    return *reinterpret_cast<u16*>(&t);
}

// ---------------------------------------------------------------------------
// C[M,N] = A[M,K] @ W[K,N] + bias[N].  A: fp32 or bf16 (TA), W/bias: fp32,
// C: bf16 or fp32 (TC). fp32->bf16 conversion inline during LDS staging.
// Block 256 = 4 waves (2x2), wave does 64x64 via 4x4 MFMA 16x16x32 tiles.
// LDS octet-swizzled: octet' = octet ^ ((row>>1)&3) -> <=2-way bank alias (free).
template <typename TA, typename TC>
__global__ __launch_bounds__(256)
void gemm_bias_k(const TA* __restrict__ A, const float* __restrict__ W,
                 const float* __restrict__ bias, TC* __restrict__ C,
                 int N, int K) {
    __shared__ __align__(16) u16 sA[128 * 32];
    __shared__ __align__(16) u16 sB[128 * 32];
    const int tid = threadIdx.x;
    const int lane = tid & 63;
    const int wv = tid >> 6;
    const int wr = wv >> 1, wc = wv & 1;
    const int m0 = blockIdx.y * 128;
    const int n0 = blockIdx.x * 128;
    const int l16 = lane & 15;
    const int koct = lane >> 4;  // 0..3

    f32x4 acc[4][4] = {};

    for (int kt = 0; kt < K; kt += 32) {
        // --- stage A tile: 128 rows x 32 k, 512 octets, 2 per thread
#pragma unroll
        for (int it = 0; it < 2; ++it) {
            int flat = tid + it * 256;
            int row = flat >> 2;
            int oc = flat & 3;
            u16x8 v;
            if constexpr (sizeof(TA) == 2) {
                v = *reinterpret_cast<const u16x8*>(
                    (const u16*)A + (size_t)(m0 + row) * K + kt + oc * 8);
            } else {
                const float* p = (const float*)A + (size_t)(m0 + row) * K + kt + oc * 8;
                f32x4 a0 = *reinterpret_cast<const f32x4*>(p);
                f32x4 a1 = *reinterpret_cast<const f32x4*>(p + 4);
#pragma unroll
                for (int e = 0; e < 4; ++e) {
                    v[e] = f2b(a0[e]);
                    v[e + 4] = f2b(a1[e]);
                }
            }
            int soc = oc ^ ((row >> 1) & 3);
            *reinterpret_cast<u16x8*>(&sA[row * 32 + soc * 8]) = v;
        }
        // --- stage B tile transposed: sB[n][k]; coalesced 4B reads along n
        {
            int n = tid & 127;
            int kb = tid >> 7;  // 0..1
#pragma unroll
            for (int it = 0; it < 2; ++it) {
                int oc = kb + it * 2;  // 0..3
                u16x8 v;
#pragma unroll
                for (int j = 0; j < 8; ++j)
                    v[j] = f2b(W[(size_t)(kt + oc * 8 + j) * N + n0 + n]);
                int soc = oc ^ ((n >> 1) & 3);
                *reinterpret_cast<u16x8*>(&sB[n * 32 + soc * 8]) = v;
            }
        }
        __syncthreads();

        bf16x8 af[4], bfr[4];
#pragma unroll
        for (int i = 0; i < 4; ++i) {
            int m = wr * 64 + i * 16 + l16;
            int soc = koct ^ ((m >> 1) & 3);
            af[i] = *reinterpret_cast<const bf16x8*>(&sA[m * 32 + soc * 8]);
        }
#pragma unroll
        for (int j = 0; j < 4; ++j) {
            int n = wc * 64 + j * 16 + l16;
            int soc = koct ^ ((n >> 1) & 3);
            bfr[j] = *reinterpret_cast<const bf16x8*>(&sB[n * 32 + soc * 8]);
        }
#pragma unroll
        for (int i = 0; i < 4; ++i)
#pragma unroll
            for (int j = 0; j < 4; ++j)
                acc[i][j] = __builtin_amdgcn_mfma_f32_16x16x32_bf16(
                    af[i], bfr[j], acc[i][j], 0, 0, 0);
        __syncthreads();
    }

    // epilogue: C/D layout col=lane&15, row=(lane>>4)*4+reg (m89-verified)
#pragma unroll
    for (int i = 0; i < 4; ++i) {
        int mbase = m0 + wr * 64 + i * 16 + (lane >> 4) * 4;
#pragma unroll
        for (int j = 0; j < 4; ++j) {
            int n = n0 + wc * 64 + j * 16 + l16;
            float bv = bias[n];
#pragma unroll
            for (int r = 0; r < 4; ++r) {
                float val = acc[i][j][r] + bv;
                if constexpr (sizeof(TC) == 2)
                    C[(size_t)(mbase + r) * N + n] = __float2bfloat16(val);
                else
                    C[(size_t)(mbase + r) * N + n] = val;
            }
        }
    }
}

// ---------------------------------------------------------------------------
// In-place RMSNorm over width 5120 (bf16 row, fp32 gain), one 256-thr block/row.
__global__ __launch_bounds__(256)
void rmsnorm_k(bf16* __restrict__ x, const float* __restrict__ g, int stride) {
    __shared__ float red[4];
    u16* row = (u16*)x + (size_t)blockIdx.x * stride;
    const int tid = threadIdx.x;
    float ss = 0.f;
    for (int oc = tid; oc < 640; oc += 256) {
        u16x8 v = *reinterpret_cast<const u16x8*>(row + oc * 8);
#pragma unroll
        for (int e = 0; e < 8; ++e) {
            float f = b2f(v[e]);
            ss += f * f;
        }
    }
#pragma unroll
    for (int off = 32; off > 0; off >>= 1) ss += __shfl_down(ss, off);
    if ((tid & 63) == 0) red[tid >> 6] = ss;
    __syncthreads();
    float rs = rsqrtf((red[0] + red[1] + red[2] + red[3]) * (1.0f / 5120.0f) + EPSF);
    for (int oc = tid; oc < 640; oc += 256) {
        u16x8 v = *reinterpret_cast<const u16x8*>(row + oc * 8);
        f32x4 g0 = *reinterpret_cast<const f32x4*>(g + oc * 8);
        f32x4 g1 = *reinterpret_cast<const f32x4*>(g + oc * 8 + 4);
        u16x8 o;
#pragma unroll
        for (int e = 0; e < 4; ++e) {
            o[e] = f2b(b2f(v[e]) * rs * g0[e]);
            o[e + 4] = f2b(b2f(v[e + 4]) * rs * g1[e]);
        }
        *reinterpret_cast<u16x8*>(row + oc * 8) = o;
    }
}

// ---------------------------------------------------------------------------
// Attention: one wave per (b,h,s) row. L=512, D=128. All bf16 buffers.
__global__ __launch_bounds__(256)
void attention_k(const bf16* __restrict__ Q, const bf16* __restrict__ KV,
                 bf16* __restrict__ O) {
    __shared__ __align__(16) float sq[4][128];
    __shared__ __align__(16) float sp[4][512];
    const int tid = threadIdx.x;
    const int wv = tid >> 6, lane = tid & 63;
    const int r = blockIdx.x * 4 + wv;
    const int b = r / (H_ * S_);
    const int rem = r - b * (H_ * S_);
    const int h = rem / S_;
    const int s = rem - h * S_;
    const u16* qrow = (const u16*)Q + (size_t)(b * S_ + s) * DIMC + h * HD_;
    const u16* kbase = (const u16*)KV + (size_t)b * L_ * (2 * DIMC) + h * HD_;
    const u16* vbase = kbase + DIMC;

    sq[wv][lane] = b2f(qrow[lane]) * SCALEF;
    sq[wv][lane + 64] = b2f(qrow[lane + 64]) * SCALEF;
    __syncthreads();

    float sc[8];
#pragma unroll
    for (int j = 0; j < 8; ++j) sc[j] = 0.f;

    for (int dc = 0; dc < 128; dc += 32) {
        float qc[32];
#pragma unroll
        for (int t = 0; t < 8; ++t) {
            f32x4 v = *reinterpret_cast<const f32x4*>(&sq[wv][dc + t * 4]);
            qc[t * 4 + 0] = v[0]; qc[t * 4 + 1] = v[1];
            qc[t * 4 + 2] = v[2]; qc[t * 4 + 3] = v[3];
        }
#pragma unroll
        for (int j = 0; j < 8; ++j) {
            const u16* kr = kbase + (size_t)(j * 64 + lane) * (2 * DIMC) + dc;
#pragma unroll
            for (int q4 = 0; q4 < 4; ++q4) {
                u16x8 kv8 = *reinterpret_cast<const u16x8*>(kr + q4 * 8);
#pragma unroll
                for (int e = 0; e < 8; ++e)
                    sc[j] = fmaf(qc[q4 * 8 + e], b2f(kv8[e]), sc[j]);
            }
        }
    }

    // fp32 softmax over L=512 (8 per lane x 64 lanes)
    float mx = sc[0];
#pragma unroll
    for (int j = 1; j < 8; ++j) mx = fmaxf(mx, sc[j]);
#pragma unroll
    for (int off = 1; off < 64; off <<= 1) mx = fmaxf(mx, __shfl_xor(mx, off));
    float sum = 0.f;
#pragma unroll
    for (int j = 0; j < 8; ++j) {
        sc[j] = __expf(sc[j] - mx);
        sum += sc[j];
    }
#pragma unroll
    for (int off = 1; off < 64; off <<= 1) sum += __shfl_xor(sum, off);
    float inv = 1.0f / sum;
#pragma unroll
    for (int j = 0; j < 8; ++j) sp[wv][j * 64 + lane] = sc[j] * inv;
    __syncthreads();

    // PV: lane owns d = 2*lane, 2*lane+1 (coalesced 4B v loads)
    float o0 = 0.f, o1 = 0.f;
    const int d0 = lane * 2;
    for (int lq = 0; lq < 128; ++lq) {
        f32x4 p4 = *reinterpret_cast<const f32x4*>(&sp[wv][lq * 4]);
#pragma unroll
        for (int e = 0; e < 4; ++e) {
            const u16* vr = vbase + (size_t)(lq * 4 + e) * (2 * DIMC) + d0;
            unsigned u = *reinterpret_cast<const unsigned*>(vr);
            o0 = fmaf(p4[e], b2f((u16)(u & 0xffffu)), o0);
            o1 = fmaf(p4[e], b2f((u16)(u >> 16)), o1);
        }
    }
    u16* orow = (u16*)O + (size_t)(b * S_ + s) * DIMC + h * HD_;
    orow[d0] = f2b(o0);
    orow[d0 + 1] = f2b(o1);
}

// ---------------------------------------------------------------------------
extern "C" void kernel_launch(void* const* d_in, const int* in_sizes, int n_in,
                              void* d_out, int out_size, void* d_ws, size_t ws_size,
                              hipStream_t stream) {
    const float* hs  = (const float*)d_in[0];
    const float* ctx = (const float*)d_in[1];
    const float* Wq  = (const float*)d_in[2];
    const float* bq  = (const float*)d_in[3];
    const float* Wkv = (const float*)d_in[4];
    const float* bkv = (const float*)d_in[5];
    const float* gq  = (const float*)d_in[6];
    const float* gk  = (const float*)d_in[7];
    const float* Wo  = (const float*)d_in[8];
    const float* bo  = (const float*)d_in[9];
    float* out = (float*)d_out;

    char* ws = (char*)d_ws;
    const size_t QBYTES = (size_t)8192 * 5120 * 2;   // 83,886,080
    const size_t KVBYTES = (size_t)1024 * 10240 * 2; // 20,971,520
    bf16* qbuf  = (bf16*)ws;
    bf16* kvbuf = (bf16*)(ws + QBYTES);
    bf16* aobuf = (bf16*)(ws + QBYTES + KVBYTES);

    dim3 blk(256);
    // q = hs @ Wq + bq   [8192,5120] (bf16)
    gemm_bias_k<float, bf16><<<dim3(40, 64), blk, 0, stream>>>(hs, Wq, bq, qbuf, 5120, 5120);
    // rmsnorm(q) * gq, in place
    rmsnorm_k<<<dim3(8192), blk, 0, stream>>>(qbuf, gq, 5120);
    // kv = ctx @ Wkv + bkv   [1024,10240] (bf16)
    gemm_bias_k<float, bf16><<<dim3(80, 8), blk, 0, stream>>>(ctx, Wkv, bkv, kvbuf, 10240, 5120);
    // rmsnorm(kv[:, :5120]) * gk, in place
    rmsnorm_k<<<dim3(1024), blk, 0, stream>>>(kvbuf, gk, 10240);
    // attention -> aobuf [8192,5120] (bf16)
    attention_k<<<dim3(81920), blk, 0, stream>>>(qbuf, kvbuf, aobuf);
    // out = aobuf @ Wo + bo  (fp32 out)
    gemm_bias_k<bf16, float><<<dim3(40, 64), blk, 0, stream>>>(aobuf, Wo, bo, out, 5120, 5120);
}